// Round 1
// baseline (73.662 us; speedup 1.0000x reference)
//
#include <hip/hip_runtime.h>

// y[i,o,n] = sum_{j,k} x_pad[j,(o-1)%28,n+k]*W[i,j,0,k] + x_pad[j,(o-2)%28,n+k]*W[i,j,1,k]
// x: (64,28,28) f32, W: (128,64,2,3) f32, y: (128,28,28) f32
//
// grid 256 = (i, o-half); i = blockIdx>>1 is block-uniform -> W loads become s_load.
// block 448 = 7 waves; lane map n=tid&31 (active n<28), o_local=tid>>5 in [0,14).
// n+-1 taps via __shfl within 32-lane halves (saves 4 of 6 global loads per j).

#define BLOCK 448

__global__ __launch_bounds__(BLOCK, 2)
void conv_shift_kernel(const float* __restrict__ x,
                       const float* __restrict__ W,
                       float* __restrict__ out) {
    const int bid = blockIdx.x;
    const int i    = bid >> 1;        // output channel, uniform per block
    const int half = bid & 1;
    const int tid = threadIdx.x;
    const int n       = tid & 31;     // column; active when n < 28
    const int o_local = tid >> 5;     // 0..13
    const int o = half * 14 + o_local;
    const int oa = (o + 27) % 28;     // row for l=0 taps
    const int ob = (o + 26) % 28;     // row for l=1 taps
    const bool act = (n < 28);

    const float* __restrict__ xa_base = x + oa * 28;
    const float* __restrict__ xb_base = x + ob * 28;
    const float* __restrict__ wrow    = W + i * 384;   // 64*6 contiguous floats

    float acc = 0.f;
    #pragma unroll 8
    for (int j = 0; j < 64; ++j) {
        // uniform address -> scalar loads into SGPRs
        const float* wj = wrow + j * 6;
        const float w0 = wj[0], w1 = wj[1], w2 = wj[2];
        const float w3 = wj[3], w4 = wj[4], w5 = wj[5];

        // center taps; lanes n>=28 supply the zero-pad for n==27's right tap
        const float xa1 = act ? xa_base[j * 784 + n] : 0.f;
        const float xb1 = act ? xb_base[j * 784 + n] : 0.f;

        float xa0 = __shfl_up(xa1, 1, 32);
        float xb0 = __shfl_up(xb1, 1, 32);
        const float xa2 = __shfl_down(xa1, 1, 32);
        const float xb2 = __shfl_down(xb1, 1, 32);
        if (n == 0) { xa0 = 0.f; xb0 = 0.f; }   // left zero-pad (shfl_up keeps own value at lane 0)

        acc += w0 * xa0 + w1 * xa1 + w2 * xa2
             + w3 * xb0 + w4 * xb1 + w5 * xb2;
    }

    if (act) {
        out[i * 784 + o * 28 + n] = acc;
    }
}

extern "C" void kernel_launch(void* const* d_in, const int* in_sizes, int n_in,
                              void* d_out, int out_size, void* d_ws, size_t ws_size,
                              hipStream_t stream) {
    const float* x = (const float*)d_in[0];   // 64*28*28
    const float* W = (const float*)d_in[1];   // 128*64*2*3
    float* out = (float*)d_out;               // 128*28*28
    conv_shift_kernel<<<256, BLOCK, 0, stream>>>(x, W, out);
}

// Round 2
// 60.966 us; speedup vs baseline: 1.2083x; 1.2083x over previous
//
#include <hip/hip_runtime.h>

// y[i,o,n] = sum_{j,k} x_pad[j,(o-1)%28,n+k]*W[i,j,0,k] + x_pad[j,(o-2)%28,n+k]*W[i,j,1,k]
// x: (64,28,28) f32, W: (128,64,2,3) f32, y: (128,28,28) f32
//
// Scatter-accumulator form: thread n loads x[.,.,n] once per (row,j) and
// accumulates contributions to y[n+1] (A0), y[n] (A1), y[n-1] (A2).
// The n+-1 taps are resolved by TWO epilogue shuffles instead of 4/iter.
// i = blockIdx>>1 is block-uniform -> W reads scalarize to s_load.

#define BLOCK 448

__global__ __launch_bounds__(BLOCK, 2)
void conv_shift_kernel(const float* __restrict__ x,
                       const float* __restrict__ W,
                       float* __restrict__ out) {
    const int bid = blockIdx.x;
    const int i    = bid >> 1;        // output channel, uniform per block
    const int half = bid & 1;
    const int tid = threadIdx.x;
    const int n       = tid & 31;     // column; active when n < 28
    const int o_local = tid >> 5;     // 0..13
    const int o = half * 14 + o_local;
    const int oa = (o + 27) % 28;     // row for l=0 taps
    const int ob = (o + 26) % 28;     // row for l=1 taps
    const bool act = (n < 28);

    const float* __restrict__ xa = x + oa * 28 + n;
    const float* __restrict__ xb = x + ob * 28 + n;
    const float* __restrict__ wp = W + i * 384;   // 64*6 contiguous floats

    float A0 = 0.f, A1 = 0.f, A2 = 0.f;   // dest n+1 / n / n-1
    #pragma unroll 16
    for (int j = 0; j < 64; ++j) {
        // lanes n>=28 contribute zeros (also keeps lane 28's A2 == 0,
        // which supplies y[27]'s right-side zero-pad tap via shfl_down)
        const float va = act ? xa[j * 784] : 0.f;
        const float vb = act ? xb[j * 784] : 0.f;

        const float w0 = wp[j*6+0], w1 = wp[j*6+1], w2 = wp[j*6+2];
        const float w3 = wp[j*6+3], w4 = wp[j*6+4], w5 = wp[j*6+5];

        A0 += w0 * va + w3 * vb;   // x[n] contributes to y[n+1] via k=0 weights
        A1 += w1 * va + w4 * vb;   // center tap
        A2 += w2 * va + w5 * vb;   // x[n] contributes to y[n-1] via k=2 weights
    }

    // gather neighbor contributions: y[n] = A1[n] + A0[n-1] + A2[n+1]
    float up = __shfl_up(A0, 1, 32);
    if (n == 0) up = 0.f;                 // left zero-pad (lane 0 has no n-1)
    const float dn = __shfl_down(A2, 1, 32);  // lane 27 <- lane 28's A2 == 0

    if (act) {
        out[i * 784 + o * 28 + n] = A1 + up + dn;
    }
}

extern "C" void kernel_launch(void* const* d_in, const int* in_sizes, int n_in,
                              void* d_out, int out_size, void* d_ws, size_t ws_size,
                              hipStream_t stream) {
    const float* x = (const float*)d_in[0];   // 64*28*28
    const float* W = (const float*)d_in[1];   // 128*64*2*3
    float* out = (float*)d_out;               // 128*28*28
    conv_shift_kernel<<<256, BLOCK, 0, stream>>>(x, W, out);
}

// Round 3
// 59.788 us; speedup vs baseline: 1.2321x; 1.0197x over previous
//
#include <hip/hip_runtime.h>

// y[i,o,n] = sum_{j,k} x_pad[j,(o-1)%28,n+k]*W[i,j,0,k] + x_pad[j,(o-2)%28,n+k]*W[i,j,1,k]
// x: (64,28,28) f32, W: (128,64,2,3) f32, y: (128,28,28) f32
//
// Scatter-accumulator form: thread n loads x[.,.,n] and accumulates
// contributions to y[n+1] (A0), y[n] (A1), y[n-1] (A2); two epilogue
// shuffles resolve the n+-1 taps. i = blockIdx>>1 is block-uniform ->
// W reads scalarize to s_load.
//
// R2 cleanup: no in-loop lane masking. Lanes n>=28 load a clamped (n=0)
// in-bounds address and accumulate garbage that is never consumed --
// the only cross-lane consumer of lane 28 is y[27]'s right-pad tap,
// which is zeroed explicitly in the epilogue (n==27 -> dn=0).
// Loop body: 2 global_load_dword + 6 v_fma + addr. Minimum for this layout.

#define BLOCK 448

__global__ __launch_bounds__(BLOCK, 2)
void conv_shift_kernel(const float* __restrict__ x,
                       const float* __restrict__ W,
                       float* __restrict__ out) {
    const int bid = blockIdx.x;
    const int i    = bid >> 1;        // output channel, uniform per block
    const int half = bid & 1;
    const int tid = threadIdx.x;
    const int n       = tid & 31;     // column; active when n < 28
    const int o_local = tid >> 5;     // 0..13
    const int o = half * 14 + o_local;
    const int oa = (o + 27) % 28;     // row for l=0 taps
    const int ob = (o + 26) % 28;     // row for l=1 taps
    const bool act = (n < 28);
    const int nc = act ? n : 0;       // clamp: inactive lanes load in-bounds garbage

    const float* __restrict__ xa = x + oa * 28 + nc;
    const float* __restrict__ xb = x + ob * 28 + nc;
    const float* __restrict__ wp = W + i * 384;   // 64*6 contiguous floats

    float A0 = 0.f, A1 = 0.f, A2 = 0.f;   // dest n+1 / n / n-1
    #pragma unroll 16
    for (int j = 0; j < 64; ++j) {
        const float va = xa[j * 784];
        const float vb = xb[j * 784];

        const float w0 = wp[j*6+0], w1 = wp[j*6+1], w2 = wp[j*6+2];
        const float w3 = wp[j*6+3], w4 = wp[j*6+4], w5 = wp[j*6+5];

        A0 += w0 * va + w3 * vb;   // x[n] -> y[n+1] (k=0 weights)
        A1 += w1 * va + w4 * vb;   // center tap
        A2 += w2 * va + w5 * vb;   // x[n] -> y[n-1] (k=2 weights)
    }

    // y[n] = A1[n] + A0[n-1] + A2[n+1]
    float up = __shfl_up(A0, 1, 32);
    if (n == 0) up = 0.f;                    // left zero-pad
    float dn = __shfl_down(A2, 1, 32);
    if (n == 27) dn = 0.f;                   // right zero-pad (lane 28 holds garbage)

    if (act) {
        out[i * 784 + o * 28 + n] = A1 + up + dn;
    }
}

extern "C" void kernel_launch(void* const* d_in, const int* in_sizes, int n_in,
                              void* d_out, int out_size, void* d_ws, size_t ws_size,
                              hipStream_t stream) {
    const float* x = (const float*)d_in[0];   // 64*28*28
    const float* W = (const float*)d_in[1];   // 128*64*2*3
    float* out = (float*)d_out;               // 128*28*28
    conv_shift_kernel<<<256, BLOCK, 0, stream>>>(x, W, out);
}